// Round 8
// baseline (272.252 us; speedup 1.0000x reference)
//
#include <hip/hip_runtime.h>

#define Bsz 4
#define Nn 2048
#define Dd 256
#define Hh 4
#define HD 64
#define NTt 5
#define ETt 6
#define LOG2E 1.4426950408889634f
#define MSUB 24.0f
#define SCLQ 0.18033688011112042f   // 0.125 * LOG2E, folded into Q at qkv time

typedef float f32x4 __attribute__((ext_vector_type(4)));
typedef __bf16 bf16x8 __attribute__((ext_vector_type(8)));
typedef unsigned int u32x4 __attribute__((ext_vector_type(4)));
typedef short s16x4 __attribute__((ext_vector_type(4)));
typedef unsigned short u16;
typedef unsigned char u8;
typedef unsigned int uint;

static __device__ __forceinline__ u16 f2bf(float f) {
  unsigned int u = __builtin_bit_cast(unsigned int, f);
  u = (u + 0x7fffu + ((u >> 16) & 1u)) >> 16;
  return (u16)u;
}

static __device__ __forceinline__ bf16x8 ld8(const u16* p) {
  return __builtin_bit_cast(bf16x8, *(const u32x4*)p);
}

#define MFMA16(a, b, c) __builtin_amdgcn_mfma_f32_16x16x32_bf16((a), (b), (c), 0, 0, 0)

// ---------------- ws layout (bytes) ----------------
#define OFF_X      0u            // f32  [8192][256]        8388608
#define OFF_XBF    8388608u      // bf16 [8192][256]        4194304
#define OFF_WQKVT  12582912u     // bf16 [768][256]         393216
#define OFF_WOT    12976128u     // bf16 [256][256]         131072
#define OFF_BQKV   13107200u     // f32  [768]              3072
#define OFF_Q      13110272u     // bf16 [B,H,N,64]         4194304
#define OFF_K      17304576u     // bf16 [B,H,N,64]         4194304
#define OFF_V      21498880u     // (spare)
#define OFF_VT     25693184u     // bf16 [B,H,64,N]         4194304
#define OFF_CTX    29887488u     // bf16 [8192][256]        4194304
#define OFF_CODES  34081792u     // u8   [B,128,32,64,16]   16777216

// ================= pack weights (transposed, bf16) =================
__global__ void pack_kernel(const float* Wq, const float* Wk, const float* Wv,
                            const float* Wo, const float* bq, const float* bk,
                            const float* bv, u16* wqkvT, u16* woT, float* bqkv) {
  int tid = blockIdx.x * 256 + threadIdx.x;
  if (tid < 196608) {                 // WqkvT[c][k] = W_which[k][cc]
    int c = tid >> 8, k = tid & 255;
    int which = c >> 8, cc = c & 255;
    const float* W = (which == 0) ? Wq : ((which == 1) ? Wk : Wv);
    wqkvT[tid] = f2bf(W[k * 256 + cc]);
  } else if (tid < 262144) {          // WoT[c][k] = Wo[k][c]
    int t2 = tid - 196608;
    int c = t2 >> 8, k = t2 & 255;
    woT[t2] = f2bf(Wo[k * 256 + c]);
  } else if (tid < 262912) {
    int c = tid - 262144;
    int which = c >> 8, cc = c & 255;
    bqkv[c] = (which == 0) ? bq[cc] : ((which == 1) ? bk[cc] : bv[cc]);
  }
}

// ================= x = nodes + node_type_embed[nt] =================
__global__ void embed_kernel(const float* nodes, const int* node_types,
                             const float* nte, float* xf, u16* xbf) {
  int t = blockIdx.x * 256 + threadIdx.x;    // 524288 threads, 4 floats each
  int flat = t * 4;
  int bn = flat >> 8, d0 = flat & 255;
  int nt = node_types[bn];
  float4 nv = *(const float4*)(nodes + flat);
  float4 ev = *(const float4*)(nte + nt * 256 + d0);
  float4 x4;
  x4.x = nv.x + ev.x; x4.y = nv.y + ev.y; x4.z = nv.z + ev.z; x4.w = nv.w + ev.w;
  *(float4*)(xf + flat) = x4;
  ushort4 xb;
  xb.x = f2bf(x4.x); xb.y = f2bf(x4.y); xb.z = f2bf(x4.z); xb.w = f2bf(x4.w);
  *(ushort4*)(xbf + flat) = xb;
}

// ================= mask pack: code = (et + 6*tm + 12*adj)*4 ===============
// TRANSPOSED fragment order for swapped-operand QK^T:
// codes[b][qt16][kt][lane][word ks][byte j] covers
//   q = qt*16 + (lane&15), kcol = kt*64 + ks*16 + (lane>>4)*4 + j
__global__ __launch_bounds__(256) void maskpack_kernel(
    const int* node_types, const int* edge_types, const float* adjacency,
    u8* codes) {
  int t = blockIdx.x * 256 + threadIdx.x;   // 1048576
  int lane = t & 63;
  int kt = (t >> 6) & 31;
  int qt = (t >> 11) & 127;
  int b = t >> 18;
  int l15 = lane & 15, l4 = lane >> 4;
  const int* etb = edge_types + (size_t)b * Nn * Nn;
  const float* adjb = adjacency + (size_t)b * Nn * Nn;
  const int* ntb = node_types + b * Nn;
  int qrow = qt * 16 + l15;
  int ntq = ntb[qrow];
  const int* etr = etb + (size_t)qrow * Nn;
  const float* adr = adjb + (size_t)qrow * Nn;
  unsigned int wds[4];
#pragma unroll
  for (int ks = 0; ks < 4; ++ks) {
    int k0 = kt * 64 + ks * 16 + l4 * 4;
    int4 et4 = *(const int4*)(etr + k0);
    float4 a4 = *(const float4*)(adr + k0);
    int4 nt4 = *(const int4*)(ntb + k0);
    int e[4] = {et4.x, et4.y, et4.z, et4.w};
    int n[4] = {nt4.x, nt4.y, nt4.z, nt4.w};
    float a[4] = {a4.x, a4.y, a4.z, a4.w};
    unsigned int acc = 0;
#pragma unroll
    for (int j = 0; j < 4; ++j) {
      int code = e[j] + ((ntq == n[j]) ? 6 : 0) + ((a[j] != 0.0f) ? 12 : 0);
      acc |= (unsigned int)(code * 4) << (8 * j);
    }
    wds[ks] = acc;
  }
  u32x4 out = {wds[0], wds[1], wds[2], wds[3]};
  *(u32x4*)(codes + (size_t)t * 16) = out;
}

// ================= QKV GEMM: [8192,256] @ [256,768] =================
// Q pre-scaled by 0.125*LOG2E (f32, before bf16 round); V written TRANSPOSED
// directly to Vtb[B,H,64,N].
__global__ __launch_bounds__(256) void qkv_kernel(const u16* xbf, const u16* wqkvT,
                                                  const float* bqkv,
                                                  u16* Qb, u16* Kb, u16* Vtb) {
  int cb = blockIdx.x;              // 0..11
  int rb = blockIdx.y;              // 0..127
  int w = threadIdx.x >> 6, lane = threadIdx.x & 63;
  int l15 = lane & 15, l4 = lane >> 4;
  int row0 = rb * 64 + w * 16;
  int col0 = cb * 64;
  const u16* xr = xbf + (size_t)(row0 + l15) * 256;
  f32x4 acc[4];
#pragma unroll
  for (int i = 0; i < 4; ++i) acc[i] = (f32x4){0.f, 0.f, 0.f, 0.f};
#pragma unroll
  for (int kst = 0; kst < 8; ++kst) {
    int k0 = kst * 32 + l4 * 8;
    bf16x8 a = ld8(xr + k0);
#pragma unroll
    for (int cs = 0; cs < 4; ++cs) {
      int col = col0 + cs * 16 + l15;
      bf16x8 bw = ld8(wqkvT + (size_t)col * 256 + k0);
      acc[cs] = MFMA16(a, bw, acc[cs]);
    }
  }
#pragma unroll
  for (int cs = 0; cs < 4; ++cs) {
    int col = col0 + cs * 16 + l15;
    float bias = bqkv[col];
    int which = col >> 8, c = col & 255;
    int h = c >> 6, hd = c & 63;
    float scale = (which == 0) ? SCLQ : 1.0f;
#pragma unroll
    for (int j = 0; j < 4; ++j) {
      int row = row0 + l4 * 4 + j;
      int bb = row >> 11, n = row & 2047;
      u16 val = f2bf((acc[cs][j] + bias) * scale);
      if (which == 2)
        Vtb[((size_t)((bb * Hh + h) * HD + hd)) * Nn + n] = val;
      else if (which == 0)
        Qb[(size_t)(((bb * Hh + h) * Nn + n)) * HD + hd] = val;
      else
        Kb[(size_t)(((bb * Hh + h) * Nn + n)) * HD + hd] = val;
    }
  }
}

// ================= attention =================
// block = (b, h, 64-row q-tile): 512 blocks x 4 waves (16 rows each), all 4
// waves share the same K/V stream (L1 reuse). K/V fragments register-direct
// from global with EXPLICIT 2-deep prefetch rotation (ka/kb, va/vb — static
// indexing). No barriers, no LDS staging; LDS = wave-private P round-trip +
// bias-LUT bpermute only. Fixed-max softmax.
__global__ __launch_bounds__(256, 2) void attn_kernel(
    const u16* Qb, const u16* Kb, const u16* Vtb, const u8* codes,
    const float* ee_g, float* attn_out, u16* ctx_ws) {
  __shared__ __align__(16) char pls[4][2048];

  int bid0 = blockIdx.x;
  int bid = ((bid0 & 7) << 6) | (bid0 >> 3);   // XCD-chunked swizzle (512 wgs)
  int qt64 = bid & 31;
  int h = (bid >> 5) & 3;
  int b = bid >> 7;
  int w = threadIdx.x >> 6, lane = threadIdx.x & 63;
  int l15 = lane & 15, l4 = lane >> 4;
  int q0 = qt64 * 64 + w * 16;
  int bh = b * Hh + h;

  // 24-entry bias LUT (log2 domain, MSUB folded in), one value per lane 0..23
  float lutv = 0.f;
  {
    int ln = lane;
    int et = ln - 6 * (ln / 6);
    int tm = (ln / 6) & 1;
    int adj = ln / 12;
    if (ln < 24)
      lutv = (ee_g[et * Hh + h] + (tm ? 0.10f : -0.05f)) * LOG2E +
             (adj ? 0.f : -1.442695041e9f) - MSUB;
  }
  int lut_i = __float_as_int(lutv);

  // Q as B-fragment (pre-scaled by SCLQ in qkv_kernel)
  const u16* Qp = Qb + (size_t)(bh * Nn + q0 + l15) * HD;
  bf16x8 bq0 = ld8(Qp + l4 * 8);
  bf16x8 bq1 = ld8(Qp + 32 + l4 * 8);

  // per-lane fragment bases (register-direct)
  const u16* Kg = Kb + (size_t)bh * Nn * HD + l15 * HD + l4 * 8;
  const u16* Vgl = Vtb + (size_t)bh * HD * Nn + (size_t)l15 * Nn + l4 * 8;
  const u32x4* cp = (const u32x4*)codes + ((size_t)(b * 128 + (q0 >> 4)) * 32) * 64 + lane;

  auto loadK = [&](bf16x8* dst, int t) {
    const u16* kp = Kg + (size_t)t * 4096;
#pragma unroll
    for (int i = 0; i < 8; ++i) dst[i] = ld8(kp + (i >> 1) * 1024 + (i & 1) * 32);
  };
  auto loadV = [&](bf16x8* dst, int t) {
    const u16* vp = Vgl + t * 64;
#pragma unroll
    for (int i = 0; i < 8; ++i) dst[i] = ld8(vp + (size_t)(i >> 1) * 16 * Nn + (i & 1) * 32);
  };

  // ---------- pass 1: accumulate exp2 sums ----------
  float accl = 0.f;
  auto qk_sum = [&](const bf16x8* kf, const u32x4& cwv) {
#pragma unroll
    for (int ks = 0; ks < 4; ++ks) {
      unsigned int cword = cwv[ks];
      f32x4 acc;
#pragma unroll
      for (int j = 0; j < 4; ++j)
        acc[j] = __int_as_float(
            __builtin_amdgcn_ds_bpermute((cword >> (8 * j)) & 0xFF, lut_i));
      acc = MFMA16(kf[ks * 2], bq0, acc);
      acc = MFMA16(kf[ks * 2 + 1], bq1, acc);
      accl += (__builtin_amdgcn_exp2f(acc[0]) + __builtin_amdgcn_exp2f(acc[1])) +
              (__builtin_amdgcn_exp2f(acc[2]) + __builtin_amdgcn_exp2f(acc[3]));
    }
  };

  {
    bf16x8 ka[8], kb2[8];
    loadK(ka, 0);
    u32x4 cwA = cp[0];
#pragma unroll 1
    for (int kt = 0; kt < 32; kt += 2) {
      u32x4 cwB = cp[(size_t)(kt + 1) * 64];
      loadK(kb2, kt + 1);
      qk_sum(ka, cwA);                 // compute even kt (prefetched)
      int t2 = (kt + 2) & 31;          // clamp; extra load of kt=0 is harmless
      u32x4 cwN = cp[(size_t)t2 * 64];
      loadK(ka, t2);
      qk_sum(kb2, cwB);                // compute odd kt
      cwA = cwN;
    }
  }
  accl += __shfl_xor(accl, 16);
  accl += __shfl_xor(accl, 32);
  bool zrow = (accl == 0.0f);
  float pscale = zrow ? 0.0f : 1.0f / accl;
  float pbias = zrow ? (1.0f / 2048.0f) : 0.0f;

  // ---------- pass 2: write attn, accumulate PV ----------
  float* attb = attn_out + (size_t)bh * Nn * Nn + (size_t)(q0 + l15) * Nn;
  char* pwave = (char*)pls + w * 2048;
  int pwbase = l15 * 128;
  int sw = (l15 & 7) << 4;
  f32x4 ctx[4];
#pragma unroll
  for (int i = 0; i < 4; ++i) ctx[i] = (f32x4){0.f, 0.f, 0.f, 0.f};

  auto pv_step = [&](const bf16x8* kf, const bf16x8* vf, const u32x4& cwv, int kt) {
#pragma unroll
    for (int ks = 0; ks < 4; ++ks) {
      unsigned int cword = cwv[ks];
      f32x4 acc;
#pragma unroll
      for (int j = 0; j < 4; ++j)
        acc[j] = __int_as_float(
            __builtin_amdgcn_ds_bpermute((cword >> (8 * j)) & 0xFF, lut_i));
      acc = MFMA16(kf[ks * 2], bq0, acc);
      acc = MFMA16(kf[ks * 2 + 1], bq1, acc);
      f32x4 p;
#pragma unroll
      for (int j = 0; j < 4; ++j)
        p[j] = __builtin_amdgcn_exp2f(acc[j]) * pscale + pbias;
      __builtin_nontemporal_store(p, (f32x4*)(attb + kt * 64 + ks * 16 + l4 * 4));
      s16x4 pb;
#pragma unroll
      for (int j = 0; j < 4; ++j)
        pb[j] = (short)__builtin_bit_cast(u16, (__bf16)p[j]);
      *(s16x4*)(pwave + pwbase + ((ks * 32 + l4 * 8) ^ sw)) = pb;
    }
    bf16x8 pa0 = ld8((const u16*)(pwave + pwbase + ((l4 * 16) ^ sw)));
    bf16x8 pa1 = ld8((const u16*)(pwave + pwbase + ((l4 * 16 + 64) ^ sw)));
#pragma unroll
    for (int d = 0; d < 4; ++d) {
      ctx[d] = MFMA16(pa0, vf[d * 2], ctx[d]);
      ctx[d] = MFMA16(pa1, vf[d * 2 + 1], ctx[d]);
    }
  };

  {
    bf16x8 ka[8], kb2[8], va[8], vb2[8];
    loadK(ka, 0);
    loadV(va, 0);
    u32x4 cwA = cp[0];
#pragma unroll 1
    for (int kt = 0; kt < 32; kt += 2) {
      u32x4 cwB = cp[(size_t)(kt + 1) * 64];
      loadK(kb2, kt + 1);
      loadV(vb2, kt + 1);
      pv_step(ka, va, cwA, kt);
      int t2 = (kt + 2) & 31;
      u32x4 cwN = cp[(size_t)t2 * 64];
      loadK(ka, t2);
      loadV(va, t2);
      pv_step(kb2, vb2, cwB, kt + 1);
      cwA = cwN;
    }
  }

#pragma unroll
  for (int ds_ = 0; ds_ < 4; ++ds_) {
    int col = h * 64 + ds_ * 16 + l15;
#pragma unroll
    for (int j = 0; j < 4; ++j) {
      int qrow = q0 + l4 * 4 + j;
      ctx_ws[(size_t)(b * Nn + qrow) * Dd + col] = f2bf(ctx[ds_][j]);
    }
  }
}

// ================= out GEMM + residual + LayerNorm =================
__global__ __launch_bounds__(256) void outln_kernel(const u16* ctxb, const u16* woT,
                                                    const float* bo, const float* xf,
                                                    const float* ln_g, const float* ln_b,
                                                    float* yout) {
  __shared__ float ytile[32][257];
  __shared__ float muS[32], rvS[32];
  int bm0 = blockIdx.x * 32;
  int w = threadIdx.x >> 6, lane = threadIdx.x & 63;
  int l15 = lane & 15, l4 = lane >> 4;
  f32x4 acc[2][4];
#pragma unroll
  for (int q = 0; q < 2; ++q)
#pragma unroll
    for (int i = 0; i < 4; ++i) acc[q][i] = (f32x4){0.f, 0.f, 0.f, 0.f};
#pragma unroll
  for (int kst = 0; kst < 8; ++kst) {
    int k0 = kst * 32 + l4 * 8;
    bf16x8 a0 = ld8(ctxb + (size_t)(bm0 + l15) * 256 + k0);
    bf16x8 a1 = ld8(ctxb + (size_t)(bm0 + 16 + l15) * 256 + k0);
#pragma unroll
    for (int ds_ = 0; ds_ < 4; ++ds_) {
      bf16x8 bw = ld8(woT + (size_t)(w * 64 + ds_ * 16 + l15) * 256 + k0);
      acc[0][ds_] = MFMA16(a0, bw, acc[0][ds_]);
      acc[1][ds_] = MFMA16(a1, bw, acc[1][ds_]);
    }
  }
#pragma unroll
  for (int qs = 0; qs < 2; ++qs)
#pragma unroll
    for (int ds_ = 0; ds_ < 4; ++ds_) {
      int col = w * 64 + ds_ * 16 + l15;
      float bof = bo[col];
#pragma unroll
      for (int j = 0; j < 4; ++j) {
        int row = qs * 16 + l4 * 4 + j;
        ytile[row][col] = acc[qs][ds_][j] + bof + xf[(size_t)(bm0 + row) * 256 + col];
      }
    }
  __syncthreads();
  int row = threadIdx.x >> 3, seg = threadIdx.x & 7;
  float ps = 0.f, pq = 0.f;
#pragma unroll
  for (int c = 0; c < 32; ++c) {
    float v = ytile[row][seg * 32 + c];
    ps += v; pq += v * v;
  }
  ps += __shfl_xor(ps, 1); pq += __shfl_xor(pq, 1);
  ps += __shfl_xor(ps, 2); pq += __shfl_xor(pq, 2);
  ps += __shfl_xor(ps, 4); pq += __shfl_xor(pq, 4);
  if (seg == 0) {
    float mu = ps * (1.0f / 256.0f);
    muS[row] = mu;
    rvS[row] = rsqrtf(pq * (1.0f / 256.0f) - mu * mu + 1e-5f);
  }
  __syncthreads();
  float mu = muS[row], rv = rvS[row];
  float* yr = yout + (size_t)(bm0 + row) * 256;
#pragma unroll
  for (int c0 = 0; c0 < 32; c0 += 4) {
    int c = seg * 32 + c0;
    float4 o;
    o.x = (ytile[row][c + 0] - mu) * rv * ln_g[c + 0] + ln_b[c + 0];
    o.y = (ytile[row][c + 1] - mu) * rv * ln_g[c + 1] + ln_b[c + 1];
    o.z = (ytile[row][c + 2] - mu) * rv * ln_g[c + 2] + ln_b[c + 2];
    o.w = (ytile[row][c + 3] - mu) * rv * ln_g[c + 3] + ln_b[c + 3];
    *(float4*)(yr + c) = o;
  }
}

extern "C" void kernel_launch(void* const* d_in, const int* in_sizes, int n_in,
                              void* d_out, int out_size, void* d_ws, size_t ws_size,
                              hipStream_t stream) {
  const float* nodes = (const float*)d_in[0];
  const int* node_types = (const int*)d_in[1];
  const int* edge_types = (const int*)d_in[2];
  const float* adjacency = (const float*)d_in[3];
  const float* nte = (const float*)d_in[4];
  const float* ee = (const float*)d_in[5];
  const float* Wq = (const float*)d_in[6];
  const float* bq = (const float*)d_in[7];
  const float* Wk = (const float*)d_in[8];
  const float* bk = (const float*)d_in[9];
  const float* Wv = (const float*)d_in[10];
  const float* bv = (const float*)d_in[11];
  const float* Wo = (const float*)d_in[12];
  const float* bo = (const float*)d_in[13];
  const float* ln_g = (const float*)d_in[14];
  const float* ln_b = (const float*)d_in[15];

  float* y = (float*)d_out;
  float* attn = y + (size_t)Bsz * Nn * Dd;

  char* ws = (char*)d_ws;
  float* xf = (float*)(ws + OFF_X);
  u16* xbf = (u16*)(ws + OFF_XBF);
  u16* wqkvT = (u16*)(ws + OFF_WQKVT);
  u16* woT = (u16*)(ws + OFF_WOT);
  float* bqkv = (float*)(ws + OFF_BQKV);
  u16* Qb = (u16*)(ws + OFF_Q);
  u16* Kb = (u16*)(ws + OFF_K);
  u16* Vtb = (u16*)(ws + OFF_VT);
  u16* ctxb = (u16*)(ws + OFF_CTX);
  u8* codes = (u8*)(ws + OFF_CODES);

  pack_kernel<<<1027, 256, 0, stream>>>(Wq, Wk, Wv, Wo, bq, bk, bv, wqkvT, woT, bqkv);
  embed_kernel<<<2048, 256, 0, stream>>>(nodes, node_types, nte, xf, xbf);
  maskpack_kernel<<<4096, 256, 0, stream>>>(node_types, edge_types, adjacency, codes);
  qkv_kernel<<<dim3(12, 128), 256, 0, stream>>>(xbf, wqkvT, bqkv, Qb, Kb, Vtb);
  attn_kernel<<<512, 256, 0, stream>>>(Qb, Kb, Vtb, codes, ee, attn, ctxb);
  outln_kernel<<<256, 256, 0, stream>>>(ctxb, woT, bo, xf, ln_g, ln_b, y);
}

// Round 9
// 203.688 us; speedup vs baseline: 1.3366x; 1.3366x over previous
//
#include <hip/hip_runtime.h>

#define Bsz 4
#define Nn 2048
#define Dd 256
#define Hh 4
#define HD 64
#define NTt 5
#define ETt 6
#define LOG2E 1.4426950408889634f
#define MSUB 24.0f
#define SCLQ 0.18033688011112042f   // 0.125 * LOG2E, folded into Q at qkv time

typedef float f32x4 __attribute__((ext_vector_type(4)));
typedef __bf16 bf16x8 __attribute__((ext_vector_type(8)));
typedef unsigned int u32x4 __attribute__((ext_vector_type(4)));
typedef short s16x4 __attribute__((ext_vector_type(4)));
typedef unsigned short u16;
typedef unsigned char u8;
typedef unsigned int uint;

static __device__ __forceinline__ u16 f2bf(float f) {
  unsigned int u = __builtin_bit_cast(unsigned int, f);
  u = (u + 0x7fffu + ((u >> 16) & 1u)) >> 16;
  return (u16)u;
}

static __device__ __forceinline__ bf16x8 ld8(const u16* p) {
  return __builtin_bit_cast(bf16x8, *(const u32x4*)p);
}

// async global->LDS, 16B per lane; LDS dest = wave-uniform base + lane*16
static __device__ __forceinline__ void stage16(const void* g, void* l) {
  __builtin_amdgcn_global_load_lds(
      (const __attribute__((address_space(1))) uint*)g,
      (__attribute__((address_space(3))) uint*)l, 16, 0, 0);
}

#define MFMA16(a, b, c) __builtin_amdgcn_mfma_f32_16x16x32_bf16((a), (b), (c), 0, 0, 0)

// ---------------- ws layout (bytes) ----------------
#define OFF_X      0u            // f32  [8192][256]        8388608
#define OFF_XBF    8388608u      // bf16 [8192][256]        4194304
#define OFF_WQKVT  12582912u     // bf16 [768][256]         393216
#define OFF_WOT    12976128u     // bf16 [256][256]         131072
#define OFF_BQKV   13107200u     // f32  [768]              3072
#define OFF_Q      13110272u     // bf16 [B,H,N,64]         4194304
#define OFF_K      17304576u     // bf16 [B,H,N,64]         4194304
#define OFF_V      21498880u     // (spare)
#define OFF_VT     25693184u     // bf16 [B,H,64,N]         4194304
#define OFF_CTX    29887488u     // bf16 [8192][256]        4194304
#define OFF_CODES  34081792u     // u8   [B,128,32,64,16]   16777216

// ================= pack weights (transposed, bf16) =================
__global__ void pack_kernel(const float* Wq, const float* Wk, const float* Wv,
                            const float* Wo, const float* bq, const float* bk,
                            const float* bv, u16* wqkvT, u16* woT, float* bqkv) {
  int tid = blockIdx.x * 256 + threadIdx.x;
  if (tid < 196608) {                 // WqkvT[c][k] = W_which[k][cc]
    int c = tid >> 8, k = tid & 255;
    int which = c >> 8, cc = c & 255;
    const float* W = (which == 0) ? Wq : ((which == 1) ? Wk : Wv);
    wqkvT[tid] = f2bf(W[k * 256 + cc]);
  } else if (tid < 262144) {          // WoT[c][k] = Wo[k][c]
    int t2 = tid - 196608;
    int c = t2 >> 8, k = t2 & 255;
    woT[t2] = f2bf(Wo[k * 256 + c]);
  } else if (tid < 262912) {
    int c = tid - 262144;
    int which = c >> 8, cc = c & 255;
    bqkv[c] = (which == 0) ? bq[cc] : ((which == 1) ? bk[cc] : bv[cc]);
  }
}

// ================= x = nodes + node_type_embed[nt] =================
__global__ void embed_kernel(const float* nodes, const int* node_types,
                             const float* nte, float* xf, u16* xbf) {
  int t = blockIdx.x * 256 + threadIdx.x;    // 524288 threads, 4 floats each
  int flat = t * 4;
  int bn = flat >> 8, d0 = flat & 255;
  int nt = node_types[bn];
  float4 nv = *(const float4*)(nodes + flat);
  float4 ev = *(const float4*)(nte + nt * 256 + d0);
  float4 x4;
  x4.x = nv.x + ev.x; x4.y = nv.y + ev.y; x4.z = nv.z + ev.z; x4.w = nv.w + ev.w;
  *(float4*)(xf + flat) = x4;
  ushort4 xb;
  xb.x = f2bf(x4.x); xb.y = f2bf(x4.y); xb.z = f2bf(x4.z); xb.w = f2bf(x4.w);
  *(ushort4*)(xbf + flat) = xb;
}

// ================= mask pack: code = (et + 6*tm + 12*adj)*4 ===============
// TRANSPOSED fragment order for swapped-operand QK^T:
// codes[b][qt16][kt][lane][word ks][byte j] covers
//   q = qt*16 + (lane&15), kcol = kt*64 + ks*16 + (lane>>4)*4 + j
__global__ __launch_bounds__(256) void maskpack_kernel(
    const int* node_types, const int* edge_types, const float* adjacency,
    u8* codes) {
  int t = blockIdx.x * 256 + threadIdx.x;   // 1048576
  int lane = t & 63;
  int kt = (t >> 6) & 31;
  int qt = (t >> 11) & 127;
  int b = t >> 18;
  int l15 = lane & 15, l4 = lane >> 4;
  const int* etb = edge_types + (size_t)b * Nn * Nn;
  const float* adjb = adjacency + (size_t)b * Nn * Nn;
  const int* ntb = node_types + b * Nn;
  int qrow = qt * 16 + l15;
  int ntq = ntb[qrow];
  const int* etr = etb + (size_t)qrow * Nn;
  const float* adr = adjb + (size_t)qrow * Nn;
  unsigned int wds[4];
#pragma unroll
  for (int ks = 0; ks < 4; ++ks) {
    int k0 = kt * 64 + ks * 16 + l4 * 4;
    int4 et4 = *(const int4*)(etr + k0);
    float4 a4 = *(const float4*)(adr + k0);
    int4 nt4 = *(const int4*)(ntb + k0);
    int e[4] = {et4.x, et4.y, et4.z, et4.w};
    int n[4] = {nt4.x, nt4.y, nt4.z, nt4.w};
    float a[4] = {a4.x, a4.y, a4.z, a4.w};
    unsigned int acc = 0;
#pragma unroll
    for (int j = 0; j < 4; ++j) {
      int code = e[j] + ((ntq == n[j]) ? 6 : 0) + ((a[j] != 0.0f) ? 12 : 0);
      acc |= (unsigned int)(code * 4) << (8 * j);
    }
    wds[ks] = acc;
  }
  u32x4 out = {wds[0], wds[1], wds[2], wds[3]};
  *(u32x4*)(codes + (size_t)t * 16) = out;
}

// ================= QKV GEMM: [8192,256] @ [256,768] =================
// Q pre-scaled by 0.125*LOG2E (f32, before bf16 round); V written TRANSPOSED
// directly to Vtb[B,H,64,N].
__global__ __launch_bounds__(256) void qkv_kernel(const u16* xbf, const u16* wqkvT,
                                                  const float* bqkv,
                                                  u16* Qb, u16* Kb, u16* Vtb) {
  int cb = blockIdx.x;              // 0..11
  int rb = blockIdx.y;              // 0..127
  int w = threadIdx.x >> 6, lane = threadIdx.x & 63;
  int l15 = lane & 15, l4 = lane >> 4;
  int row0 = rb * 64 + w * 16;
  int col0 = cb * 64;
  const u16* xr = xbf + (size_t)(row0 + l15) * 256;
  f32x4 acc[4];
#pragma unroll
  for (int i = 0; i < 4; ++i) acc[i] = (f32x4){0.f, 0.f, 0.f, 0.f};
#pragma unroll
  for (int kst = 0; kst < 8; ++kst) {
    int k0 = kst * 32 + l4 * 8;
    bf16x8 a = ld8(xr + k0);
#pragma unroll
    for (int cs = 0; cs < 4; ++cs) {
      int col = col0 + cs * 16 + l15;
      bf16x8 bw = ld8(wqkvT + (size_t)col * 256 + k0);
      acc[cs] = MFMA16(a, bw, acc[cs]);
    }
  }
#pragma unroll
  for (int cs = 0; cs < 4; ++cs) {
    int col = col0 + cs * 16 + l15;
    float bias = bqkv[col];
    int which = col >> 8, c = col & 255;
    int h = c >> 6, hd = c & 63;
    float scale = (which == 0) ? SCLQ : 1.0f;
#pragma unroll
    for (int j = 0; j < 4; ++j) {
      int row = row0 + l4 * 4 + j;
      int bb = row >> 11, n = row & 2047;
      u16 val = f2bf((acc[cs][j] + bias) * scale);
      if (which == 2)
        Vtb[((size_t)((bb * Hh + h) * HD + hd)) * Nn + n] = val;
      else if (which == 0)
        Qb[(size_t)(((bb * Hh + h) * Nn + n)) * HD + hd] = val;
      else
        Kb[(size_t)(((bb * Hh + h) * Nn + n)) * HD + hd] = val;
    }
  }
}

// ================= attention =================
// block = (b, h, 32-row q-tile): 1024 blocks x 2 waves (16 rows each).
// 4 blocks/CU (36KB LDS) -> 16 waves/CU. K/V tiles double-buffered in LDS via
// global_load_lds (each wave stages half the tile), XOR-swizzled source+read.
// Swapped-operand QK^T with bias-LUT-as-C-init (bpermute); fixed-max softmax;
// counted vmcnt barriers leave attn stores + codes prefetch in flight.
__global__ __launch_bounds__(128, 4) void attn_kernel(
    const u16* Qb, const u16* Kb, const u16* Vtb, const u8* codes,
    const float* ee_g, float* attn_out, u16* ctx_ws) {
  __shared__ __align__(16) char kls[2][8192];
  __shared__ __align__(16) char vls[2][8192];
  __shared__ __align__(16) char pls[2][2048];

  int bid0 = blockIdx.x;
  int bid = ((bid0 & 7) << 7) | (bid0 >> 3);   // XCD-chunked swizzle (1024 wgs)
  int qt32 = bid & 63;
  int h = (bid >> 6) & 3;
  int b = bid >> 8;
  int w = threadIdx.x >> 6, lane = threadIdx.x & 63;
  int l15 = lane & 15, l4 = lane >> 4;
  int q0 = qt32 * 32 + w * 16;
  int bh = b * Hh + h;

  // 24-entry bias LUT (log2 domain, MSUB folded in), one value per lane 0..23
  float lutv = 0.f;
  {
    int ln = lane;
    int et = ln - 6 * (ln / 6);
    int tm = (ln / 6) & 1;
    int adj = ln / 12;
    if (ln < 24)
      lutv = (ee_g[et * Hh + h] + (tm ? 0.10f : -0.05f)) * LOG2E +
             (adj ? 0.f : -1.442695041e9f) - MSUB;
  }
  int lut_i = __float_as_int(lutv);

  // Q as B-fragment (pre-scaled by SCLQ in qkv_kernel)
  const u16* Qp = Qb + (size_t)(bh * Nn + q0 + l15) * HD;
  bf16x8 bq0 = ld8(Qp + l4 * 8);
  bf16x8 bq1 = ld8(Qp + 32 + l4 * 8);

  const char* Kg = (const char*)(Kb + (size_t)bh * Nn * HD);
  const char* Vg = (const char*)(Vtb + (size_t)bh * HD * Nn);
  const u32x4* cp = (const u32x4*)codes + ((size_t)(b * 128 + (q0 >> 4)) * 32) * 64;

  // staging offsets: LDS[o] = G[swz(o)], swz(o) = o ^ (((o>>7)&7)<<4)
  // each wave stages 4KB of the 8KB tile: o_i = w*4096 + i*1024 + lane*16
  int oS[4], kswS[4];
  const char* VgR[4];
#pragma unroll
  for (int i = 0; i < 4; ++i) {
    int o = w * 4096 + i * 1024 + lane * 16;
    int s = o ^ (((o >> 7) & 7) << 4);
    oS[i] = o;
    kswS[i] = s;
    VgR[i] = Vg + (size_t)(o >> 7) * (Nn * 2) + (s & 127);
  }

  // swizzled ds_read base: tile byte a = row*128 + l4*16 (+64), row = ks*16+l15
  int sw = (l15 & 7) << 4;
  int ra = (l15 * 128 + l4 * 16) ^ sw;

  // ---------- pass 1: accumulate exp2 sums ----------
#pragma unroll
  for (int i = 0; i < 4; ++i) stage16(Kg + kswS[i], (char*)kls + oS[i]);
  u32x4 cw = cp[lane];
  __syncthreads();

  float accl = 0.f;
#pragma unroll 1
  for (int kt = 0; kt < 32; ++kt) {
    int cb = kt & 1, nb = cb ^ 1;
    u32x4 cwn = cw;
    if (kt < 31) {
      const char* Kn = Kg + (size_t)(kt + 1) * 8192;
#pragma unroll
      for (int i = 0; i < 4; ++i) stage16(Kn + kswS[i], (char*)kls + nb * 8192 + oS[i]);
      cwn = cp[(kt + 1) * 64 + lane];
    }
    __builtin_amdgcn_sched_barrier(0);
    const char* kcur = (const char*)kls + cb * 8192;
#pragma unroll
    for (int ks = 0; ks < 4; ++ks) {
      unsigned int cword = cw[ks];
      f32x4 acc;
#pragma unroll
      for (int j = 0; j < 4; ++j)
        acc[j] = __int_as_float(
            __builtin_amdgcn_ds_bpermute((cword >> (8 * j)) & 0xFF, lut_i));
      acc = MFMA16(ld8((const u16*)(kcur + ra + ks * 2048)), bq0, acc);
      acc = MFMA16(ld8((const u16*)(kcur + (ra ^ 64) + ks * 2048)), bq1, acc);
      accl += (__builtin_amdgcn_exp2f(acc[0]) + __builtin_amdgcn_exp2f(acc[1])) +
              (__builtin_amdgcn_exp2f(acc[2]) + __builtin_amdgcn_exp2f(acc[3]));
    }
    asm volatile("s_waitcnt vmcnt(1) lgkmcnt(0)" ::: "memory");
    __builtin_amdgcn_s_barrier();
    cw = cwn;
  }
  accl += __shfl_xor(accl, 16);
  accl += __shfl_xor(accl, 32);
  bool zrow = (accl == 0.0f);
  float pscale = zrow ? 0.0f : 1.0f / accl;
  float pbias = zrow ? (1.0f / 2048.0f) : 0.0f;

  // ---------- pass 2: write attn, accumulate PV ----------
  float* attb = attn_out + (size_t)bh * Nn * Nn + (size_t)(q0 + l15) * Nn;
  char* pwave = (char*)pls + w * 2048;
  int pwbase = l15 * 128;
  f32x4 ctx[4];
#pragma unroll
  for (int i = 0; i < 4; ++i) ctx[i] = (f32x4){0.f, 0.f, 0.f, 0.f};

#pragma unroll
  for (int i = 0; i < 4; ++i) {
    stage16(Kg + kswS[i], (char*)kls + oS[i]);
    stage16(VgR[i], (char*)vls + oS[i]);
  }
  cw = cp[lane];
  __syncthreads();

#pragma unroll 1
  for (int kt = 0; kt < 32; ++kt) {
    int cb = kt & 1, nb = cb ^ 1;
    u32x4 cwn = cw;
    if (kt < 31) {
      const char* Kn = Kg + (size_t)(kt + 1) * 8192;
#pragma unroll
      for (int i = 0; i < 4; ++i) {
        stage16(Kn + kswS[i], (char*)kls + nb * 8192 + oS[i]);
        stage16(VgR[i] + (size_t)(kt + 1) * 128, (char*)vls + nb * 8192 + oS[i]);
      }
      cwn = cp[(kt + 1) * 64 + lane];
    }
    __builtin_amdgcn_sched_barrier(0);
    const char* kcur = (const char*)kls + cb * 8192;
    const char* vcur = (const char*)vls + cb * 8192;
#pragma unroll
    for (int ks = 0; ks < 4; ++ks) {
      unsigned int cword = cw[ks];
      f32x4 acc;
#pragma unroll
      for (int j = 0; j < 4; ++j)
        acc[j] = __int_as_float(
            __builtin_amdgcn_ds_bpermute((cword >> (8 * j)) & 0xFF, lut_i));
      acc = MFMA16(ld8((const u16*)(kcur + ra + ks * 2048)), bq0, acc);
      acc = MFMA16(ld8((const u16*)(kcur + (ra ^ 64) + ks * 2048)), bq1, acc);
      f32x4 p;
#pragma unroll
      for (int j = 0; j < 4; ++j)
        p[j] = __builtin_amdgcn_exp2f(acc[j]) * pscale + pbias;
      __builtin_nontemporal_store(p, (f32x4*)(attb + kt * 64 + ks * 16 + l4 * 4));
      s16x4 pb;
#pragma unroll
      for (int j = 0; j < 4; ++j)
        pb[j] = (short)__builtin_bit_cast(u16, (__bf16)p[j]);
      *(s16x4*)(pwave + pwbase + ((ks * 32 + l4 * 8) ^ sw)) = pb;
    }
    // PV: read P as A-fragments, staged V as B-fragments
    bf16x8 pa0 = ld8((const u16*)(pwave + pwbase + ((l4 * 16) ^ sw)));
    bf16x8 pa1 = ld8((const u16*)(pwave + pwbase + ((l4 * 16 + 64) ^ sw)));
#pragma unroll
    for (int ds_ = 0; ds_ < 4; ++ds_) {
      bf16x8 v0 = ld8((const u16*)(vcur + ra + ds_ * 2048));
      bf16x8 v1 = ld8((const u16*)(vcur + (ra ^ 64) + ds_ * 2048));
      ctx[ds_] = MFMA16(pa0, v0, ctx[ds_]);
      ctx[ds_] = MFMA16(pa1, v1, ctx[ds_]);
    }
    // counted barrier: my 8 stage gl_lds must land (cross-wave publish);
    // codes prefetch + 4 nontemporal stores may stay in flight.
    asm volatile("s_waitcnt vmcnt(5) lgkmcnt(0)" ::: "memory");
    __builtin_amdgcn_s_barrier();
    cw = cwn;
  }

#pragma unroll
  for (int ds_ = 0; ds_ < 4; ++ds_) {
    int col = h * 64 + ds_ * 16 + l15;
#pragma unroll
    for (int j = 0; j < 4; ++j) {
      int qrow = q0 + l4 * 4 + j;
      ctx_ws[(size_t)(b * Nn + qrow) * Dd + col] = f2bf(ctx[ds_][j]);
    }
  }
}

// ================= out GEMM + residual + LayerNorm =================
__global__ __launch_bounds__(256) void outln_kernel(const u16* ctxb, const u16* woT,
                                                    const float* bo, const float* xf,
                                                    const float* ln_g, const float* ln_b,
                                                    float* yout) {
  __shared__ float ytile[32][257];
  __shared__ float muS[32], rvS[32];
  int bm0 = blockIdx.x * 32;
  int w = threadIdx.x >> 6, lane = threadIdx.x & 63;
  int l15 = lane & 15, l4 = lane >> 4;
  f32x4 acc[2][4];
#pragma unroll
  for (int q = 0; q < 2; ++q)
#pragma unroll
    for (int i = 0; i < 4; ++i) acc[q][i] = (f32x4){0.f, 0.f, 0.f, 0.f};
#pragma unroll
  for (int kst = 0; kst < 8; ++kst) {
    int k0 = kst * 32 + l4 * 8;
    bf16x8 a0 = ld8(ctxb + (size_t)(bm0 + l15) * 256 + k0);
    bf16x8 a1 = ld8(ctxb + (size_t)(bm0 + 16 + l15) * 256 + k0);
#pragma unroll
    for (int ds_ = 0; ds_ < 4; ++ds_) {
      bf16x8 bw = ld8(woT + (size_t)(w * 64 + ds_ * 16 + l15) * 256 + k0);
      acc[0][ds_] = MFMA16(a0, bw, acc[0][ds_]);
      acc[1][ds_] = MFMA16(a1, bw, acc[1][ds_]);
    }
  }
#pragma unroll
  for (int qs = 0; qs < 2; ++qs)
#pragma unroll
    for (int ds_ = 0; ds_ < 4; ++ds_) {
      int col = w * 64 + ds_ * 16 + l15;
      float bof = bo[col];
#pragma unroll
      for (int j = 0; j < 4; ++j) {
        int row = qs * 16 + l4 * 4 + j;
        ytile[row][col] = acc[qs][ds_][j] + bof + xf[(size_t)(bm0 + row) * 256 + col];
      }
    }
  __syncthreads();
  int row = threadIdx.x >> 3, seg = threadIdx.x & 7;
  float ps = 0.f, pq = 0.f;
#pragma unroll
  for (int c = 0; c < 32; ++c) {
    float v = ytile[row][seg * 32 + c];
    ps += v; pq += v * v;
  }
  ps += __shfl_xor(ps, 1); pq += __shfl_xor(pq, 1);
  ps += __shfl_xor(ps, 2); pq += __shfl_xor(pq, 2);
  ps += __shfl_xor(ps, 4); pq += __shfl_xor(pq, 4);
  if (seg == 0) {
    float mu = ps * (1.0f / 256.0f);
    muS[row] = mu;
    rvS[row] = rsqrtf(pq * (1.0f / 256.0f) - mu * mu + 1e-5f);
  }
  __syncthreads();
  float mu = muS[row], rv = rvS[row];
  float* yr = yout + (size_t)(bm0 + row) * 256;
#pragma unroll
  for (int c0 = 0; c0 < 32; c0 += 4) {
    int c = seg * 32 + c0;
    float4 o;
    o.x = (ytile[row][c + 0] - mu) * rv * ln_g[c + 0] + ln_b[c + 0];
    o.y = (ytile[row][c + 1] - mu) * rv * ln_g[c + 1] + ln_b[c + 1];
    o.z = (ytile[row][c + 2] - mu) * rv * ln_g[c + 2] + ln_b[c + 2];
    o.w = (ytile[row][c + 3] - mu) * rv * ln_g[c + 3] + ln_b[c + 3];
    *(float4*)(yr + c) = o;
  }
}

extern "C" void kernel_launch(void* const* d_in, const int* in_sizes, int n_in,
                              void* d_out, int out_size, void* d_ws, size_t ws_size,
                              hipStream_t stream) {
  const float* nodes = (const float*)d_in[0];
  const int* node_types = (const int*)d_in[1];
  const int* edge_types = (const int*)d_in[2];
  const float* adjacency = (const float*)d_in[3];
  const float* nte = (const float*)d_in[4];
  const float* ee = (const float*)d_in[5];
  const float* Wq = (const float*)d_in[6];
  const float* bq = (const float*)d_in[7];
  const float* Wk = (const float*)d_in[8];
  const float* bk = (const float*)d_in[9];
  const float* Wv = (const float*)d_in[10];
  const float* bv = (const float*)d_in[11];
  const float* Wo = (const float*)d_in[12];
  const float* bo = (const float*)d_in[13];
  const float* ln_g = (const float*)d_in[14];
  const float* ln_b = (const float*)d_in[15];

  float* y = (float*)d_out;
  float* attn = y + (size_t)Bsz * Nn * Dd;

  char* ws = (char*)d_ws;
  float* xf = (float*)(ws + OFF_X);
  u16* xbf = (u16*)(ws + OFF_XBF);
  u16* wqkvT = (u16*)(ws + OFF_WQKVT);
  u16* woT = (u16*)(ws + OFF_WOT);
  float* bqkv = (float*)(ws + OFF_BQKV);
  u16* Qb = (u16*)(ws + OFF_Q);
  u16* Kb = (u16*)(ws + OFF_K);
  u16* Vtb = (u16*)(ws + OFF_VT);
  u16* ctxb = (u16*)(ws + OFF_CTX);
  u8* codes = (u8*)(ws + OFF_CODES);

  pack_kernel<<<1027, 256, 0, stream>>>(Wq, Wk, Wv, Wo, bq, bk, bv, wqkvT, woT, bqkv);
  embed_kernel<<<2048, 256, 0, stream>>>(nodes, node_types, nte, xf, xbf);
  maskpack_kernel<<<4096, 256, 0, stream>>>(node_types, edge_types, adjacency, codes);
  qkv_kernel<<<dim3(12, 128), 256, 0, stream>>>(xbf, wqkvT, bqkv, Qb, Kb, Vtb);
  attn_kernel<<<1024, 128, 0, stream>>>(Qb, Kb, Vtb, codes, ee, attn, ctxb);
  outln_kernel<<<256, 256, 0, stream>>>(ctxb, woT, bo, xf, ln_g, ln_b, y);
}

// Round 10
// 192.283 us; speedup vs baseline: 1.4159x; 1.0593x over previous
//
#include <hip/hip_runtime.h>

#define Bsz 4
#define Nn 2048
#define Dd 256
#define Hh 4
#define HD 64
#define NTt 5
#define ETt 6
#define LOG2E 1.4426950408889634f
#define MSUB 24.0f
#define SCLQ 0.18033688011112042f   // 0.125 * LOG2E, folded into Q at qkv time

typedef float f32x4 __attribute__((ext_vector_type(4)));
typedef __bf16 bf16x8 __attribute__((ext_vector_type(8)));
typedef unsigned int u32x4 __attribute__((ext_vector_type(4)));
typedef short s16x4 __attribute__((ext_vector_type(4)));
typedef unsigned short u16;
typedef unsigned char u8;
typedef unsigned int uint;

static __device__ __forceinline__ u16 f2bf(float f) {
  unsigned int u = __builtin_bit_cast(unsigned int, f);
  u = (u + 0x7fffu + ((u >> 16) & 1u)) >> 16;
  return (u16)u;
}

static __device__ __forceinline__ bf16x8 ld8(const u16* p) {
  return __builtin_bit_cast(bf16x8, *(const u32x4*)p);
}

// async global->LDS, 16B per lane; LDS dest = wave-uniform base + lane*16
static __device__ __forceinline__ void stage16(const void* g, void* l) {
  __builtin_amdgcn_global_load_lds(
      (const __attribute__((address_space(1))) uint*)g,
      (__attribute__((address_space(3))) uint*)l, 16, 0, 0);
}

#define MFMA16(a, b, c) __builtin_amdgcn_mfma_f32_16x16x32_bf16((a), (b), (c), 0, 0, 0)

// ---------------- ws layout (bytes) ----------------
#define OFF_X      0u            // f32  [8192][256]        8388608
#define OFF_XBF    8388608u      // bf16 [8192][256]        4194304
#define OFF_WQKVT  12582912u     // bf16 [768][256]         393216
#define OFF_WOT    12976128u     // bf16 [256][256]         131072
#define OFF_BQKV   13107200u     // f32  [768]              3072
#define OFF_Q      13110272u     // bf16 [B,H,N,64]         4194304
#define OFF_K      17304576u     // bf16 [B,H,N,64]         4194304
#define OFF_V      21498880u     // bf16 [B,H,N,64]         4194304
#define OFF_VT     25693184u     // bf16 [B,H,64,N]         4194304
#define OFF_CTX    29887488u     // bf16 [8192][256]        4194304
#define OFF_CODES  34081792u     // u8   [B,128,32,64,16]   16777216

// ================= pack weights (transposed, bf16) =================
__global__ void pack_kernel(const float* Wq, const float* Wk, const float* Wv,
                            const float* Wo, const float* bq, const float* bk,
                            const float* bv, u16* wqkvT, u16* woT, float* bqkv) {
  int tid = blockIdx.x * 256 + threadIdx.x;
  if (tid < 196608) {                 // WqkvT[c][k] = W_which[k][cc]
    int c = tid >> 8, k = tid & 255;
    int which = c >> 8, cc = c & 255;
    const float* W = (which == 0) ? Wq : ((which == 1) ? Wk : Wv);
    wqkvT[tid] = f2bf(W[k * 256 + cc]);
  } else if (tid < 262144) {          // WoT[c][k] = Wo[k][c]
    int t2 = tid - 196608;
    int c = t2 >> 8, k = t2 & 255;
    woT[t2] = f2bf(Wo[k * 256 + c]);
  } else if (tid < 262912) {
    int c = tid - 262144;
    int which = c >> 8, cc = c & 255;
    bqkv[c] = (which == 0) ? bq[cc] : ((which == 1) ? bk[cc] : bv[cc]);
  }
}

// ================= x = nodes + node_type_embed[nt] =================
__global__ void embed_kernel(const float* nodes, const int* node_types,
                             const float* nte, float* xf, u16* xbf) {
  int t = blockIdx.x * 256 + threadIdx.x;    // 524288 threads, 4 floats each
  int flat = t * 4;
  int bn = flat >> 8, d0 = flat & 255;
  int nt = node_types[bn];
  float4 nv = *(const float4*)(nodes + flat);
  float4 ev = *(const float4*)(nte + nt * 256 + d0);
  float4 x4;
  x4.x = nv.x + ev.x; x4.y = nv.y + ev.y; x4.z = nv.z + ev.z; x4.w = nv.w + ev.w;
  *(float4*)(xf + flat) = x4;
  ushort4 xb;
  xb.x = f2bf(x4.x); xb.y = f2bf(x4.y); xb.z = f2bf(x4.z); xb.w = f2bf(x4.w);
  *(ushort4*)(xbf + flat) = xb;
}

// ================= mask pack: code = (et + 6*tm + 12*adj)*4 ===============
// TRANSPOSED fragment order for swapped-operand QK^T:
// codes[b][qt16][kt][lane][word ks][byte j] covers
//   q = qt*16 + (lane&15), kcol = kt*64 + ks*16 + (lane>>4)*4 + j
__global__ __launch_bounds__(256) void maskpack_kernel(
    const int* node_types, const int* edge_types, const float* adjacency,
    u8* codes) {
  int t = blockIdx.x * 256 + threadIdx.x;   // 1048576
  int lane = t & 63;
  int kt = (t >> 6) & 31;
  int qt = (t >> 11) & 127;
  int b = t >> 18;
  int l15 = lane & 15, l4 = lane >> 4;
  const int* etb = edge_types + (size_t)b * Nn * Nn;
  const float* adjb = adjacency + (size_t)b * Nn * Nn;
  const int* ntb = node_types + b * Nn;
  int qrow = qt * 16 + l15;
  int ntq = ntb[qrow];
  const int* etr = etb + (size_t)qrow * Nn;
  const float* adr = adjb + (size_t)qrow * Nn;
  unsigned int wds[4];
#pragma unroll
  for (int ks = 0; ks < 4; ++ks) {
    int k0 = kt * 64 + ks * 16 + l4 * 4;
    int4 et4 = *(const int4*)(etr + k0);
    float4 a4 = *(const float4*)(adr + k0);
    int4 nt4 = *(const int4*)(ntb + k0);
    int e[4] = {et4.x, et4.y, et4.z, et4.w};
    int n[4] = {nt4.x, nt4.y, nt4.z, nt4.w};
    float a[4] = {a4.x, a4.y, a4.z, a4.w};
    unsigned int acc = 0;
#pragma unroll
    for (int j = 0; j < 4; ++j) {
      int code = e[j] + ((ntq == n[j]) ? 6 : 0) + ((a[j] != 0.0f) ? 12 : 0);
      acc |= (unsigned int)(code * 4) << (8 * j);
    }
    wds[ks] = acc;
  }
  u32x4 out = {wds[0], wds[1], wds[2], wds[3]};
  *(u32x4*)(codes + (size_t)t * 16) = out;
}

// ================= QKV GEMM: [8192,256] @ [256,768] =================
// Q output is pre-scaled by 0.125*LOG2E (in f32, before bf16 round).
__global__ __launch_bounds__(256) void qkv_kernel(const u16* xbf, const u16* wqkvT,
                                                  const float* bqkv,
                                                  u16* Qb, u16* Kb, u16* Vb) {
  int cb = blockIdx.x;              // 0..11
  int rb = blockIdx.y;              // 0..127
  int w = threadIdx.x >> 6, lane = threadIdx.x & 63;
  int l15 = lane & 15, l4 = lane >> 4;
  int row0 = rb * 64 + w * 16;
  int col0 = cb * 64;
  const u16* xr = xbf + (size_t)(row0 + l15) * 256;
  f32x4 acc[4];
#pragma unroll
  for (int i = 0; i < 4; ++i) acc[i] = (f32x4){0.f, 0.f, 0.f, 0.f};
#pragma unroll
  for (int kst = 0; kst < 8; ++kst) {
    int k0 = kst * 32 + l4 * 8;
    bf16x8 a = ld8(xr + k0);
#pragma unroll
    for (int cs = 0; cs < 4; ++cs) {
      int col = col0 + cs * 16 + l15;
      bf16x8 bw = ld8(wqkvT + (size_t)col * 256 + k0);
      acc[cs] = MFMA16(a, bw, acc[cs]);
    }
  }
#pragma unroll
  for (int cs = 0; cs < 4; ++cs) {
    int col = col0 + cs * 16 + l15;
    float bias = bqkv[col];
    int which = col >> 8, c = col & 255;
    int h = c >> 6, hd = c & 63;
    float scale = (which == 0) ? SCLQ : 1.0f;
    u16* dst = (which == 0) ? Qb : ((which == 1) ? Kb : Vb);
#pragma unroll
    for (int j = 0; j < 4; ++j) {
      int row = row0 + l4 * 4 + j;
      int bb = row >> 11, n = row & 2047;
      dst[(size_t)(((bb * Hh + h) * Nn + n)) * HD + hd] = f2bf((acc[cs][j] + bias) * scale);
    }
  }
}

// ================= V transpose: [B,H,N,64] -> [B,H,64,N] =================
__global__ __launch_bounds__(256) void vtrans_kernel(const u16* Vb, u16* Vtb) {
  int bh = blockIdx.y;              // 0..15
  int d = threadIdx.x & 63;
  int nc = threadIdx.x >> 6;        // 0..3
  int n0 = blockIdx.x * 64 + nc * 16;
  const u16* Vp = Vb + (size_t)bh * Nn * HD;
  union { u16 a[16]; u32x4 v[2]; } tmp;
#pragma unroll
  for (int i = 0; i < 16; ++i) tmp.a[i] = Vp[(size_t)(n0 + i) * HD + d];
  u16* dst = Vtb + ((size_t)bh * HD + d) * Nn + n0;
  *(u32x4*)dst = tmp.v[0];
  *(u32x4*)(dst + 8) = tmp.v[1];
}

// ================= attention =================
// block = (b, h, 64-row q-tile): 512 blocks x 4 waves (16 rows each).
// K/V TRIPLE-buffered in LDS, staged DEPTH-2 ahead via global_load_lds:
// iteration kt stages tile kt+2; end-of-iter s_waitcnt vmcnt(8) drains only
// tile kt+1's stage (leaving kt+2's stage + this iter's 4 attn stores in
// flight) so each stage has ~2 compute bodies of latency headroom.
// Swapped-operand QK^T with bias-LUT-as-C-init (bpermute); fixed-max softmax.
__global__ __launch_bounds__(256) void attn_kernel(
    const u16* Qb, const u16* Kb, const u16* Vtb, const u8* codes,
    const float* ee_g, float* attn_out, u16* ctx_ws) {
  __shared__ __align__(16) char kls[3][8192];
  __shared__ __align__(16) char vls[3][8192];
  __shared__ __align__(16) char pls[4][2048];

  int bid0 = blockIdx.x;
  int bid = ((bid0 & 7) << 6) | (bid0 >> 3);   // XCD-chunked swizzle (512 wgs)
  int qt64 = bid & 31;
  int h = (bid >> 5) & 3;
  int b = bid >> 7;
  int w = threadIdx.x >> 6, lane = threadIdx.x & 63;
  int l15 = lane & 15, l4 = lane >> 4;
  int q0 = qt64 * 64 + w * 16;
  int bh = b * Hh + h;

  // 24-entry bias LUT (log2 domain, MSUB folded in), one value per lane 0..23
  float lutv = 0.f;
  {
    int ln = lane;
    int et = ln - 6 * (ln / 6);
    int tm = (ln / 6) & 1;
    int adj = ln / 12;
    if (ln < 24)
      lutv = (ee_g[et * Hh + h] + (tm ? 0.10f : -0.05f)) * LOG2E +
             (adj ? 0.f : -1.442695041e9f) - MSUB;
  }
  int lut_i = __float_as_int(lutv);

  // Q as B-fragment (pre-scaled by SCLQ in qkv_kernel)
  const u16* Qp = Qb + (size_t)(bh * Nn + q0 + l15) * HD;
  bf16x8 bq0 = ld8(Qp + l4 * 8);
  bf16x8 bq1 = ld8(Qp + 32 + l4 * 8);

  const char* Kg = (const char*)(Kb + (size_t)bh * Nn * HD);
  const char* Vg = (const char*)(Vtb + (size_t)bh * HD * Nn);
  const u32x4* cp = (const u32x4*)codes + ((size_t)(b * 128 + (q0 >> 4)) * 32) * 64;

  // staging offsets: LDS[o] = G[swz(o)], swz(o) = o ^ (((o>>7)&7)<<4)
  int oT0 = w * 2048 + lane * 16;
  int oT1 = oT0 + 1024;
  int ksw0 = oT0 ^ (((oT0 >> 7) & 7) << 4);
  int ksw1 = oT1 ^ (((oT1 >> 7) & 7) << 4);
  const char* VgR0 = Vg + (size_t)(oT0 >> 7) * (Nn * 2) + (ksw0 & 127);
  const char* VgR1 = Vg + (size_t)(oT1 >> 7) * (Nn * 2) + (ksw1 & 127);

  // swizzled ds_read base: tile byte a = row*128 + l4*16 (+64), row = ks*16+l15
  int sw = (l15 & 7) << 4;
  int ra = (l15 * 128 + l4 * 16) ^ sw;

  // ---------- pass 1: accumulate exp2 sums ----------
  u32x4 cw = cp[lane];                        // code(0), oldest in FIFO
  __builtin_amdgcn_sched_barrier(0);
  {
    char* kd = (char*)kls + w * 2048;
    stage16(Kg + ksw0, kd);                   // K0 -> buf0
    stage16(Kg + ksw1, kd + 1024);
    stage16(Kg + 8192 + ksw0, kd + 8192);     // K1 -> buf1
    stage16(Kg + 8192 + ksw1, kd + 8192 + 1024);
  }
  asm volatile("s_waitcnt vmcnt(2) lgkmcnt(0)" ::: "memory");  // drain cw,K0
  __builtin_amdgcn_s_barrier();

  float accl = 0.f;
  int cb = 0;
#pragma unroll 1
  for (int kt = 0; kt < 32; ++kt) {
    u32x4 cwn = cw;
    if (kt < 31) cwn = cp[(kt + 1) * 64 + lane];   // code first (oldest)
    __builtin_amdgcn_sched_barrier(0);
    if (kt < 30) {
      int nb = cb ? cb - 1 : 2;                    // (kt+2) % 3
      const char* Kn = Kg + (size_t)(kt + 2) * 8192;
      char* kd = (char*)kls + nb * 8192 + w * 2048;
      stage16(Kn + ksw0, kd);
      stage16(Kn + ksw1, kd + 1024);
    }
    __builtin_amdgcn_sched_barrier(0);
    const char* kcur = (const char*)kls + cb * 8192;
#pragma unroll
    for (int ks = 0; ks < 4; ++ks) {
      unsigned int cword = cw[ks];
      f32x4 acc;
#pragma unroll
      for (int j = 0; j < 4; ++j)
        acc[j] = __int_as_float(
            __builtin_amdgcn_ds_bpermute((cword >> (8 * j)) & 0xFF, lut_i));
      acc = MFMA16(ld8((const u16*)(kcur + ra + ks * 2048)), bq0, acc);
      acc = MFMA16(ld8((const u16*)(kcur + (ra ^ 64) + ks * 2048)), bq1, acc);
      accl += (__builtin_amdgcn_exp2f(acc[0]) + __builtin_amdgcn_exp2f(acc[1])) +
              (__builtin_amdgcn_exp2f(acc[2]) + __builtin_amdgcn_exp2f(acc[3]));
    }
    // drain stage(kt+1)+code(kt+1); leave stage(kt+2) (2) in flight
    if (kt < 30)
      asm volatile("s_waitcnt vmcnt(2) lgkmcnt(0)" ::: "memory");
    else if (kt == 30)
      asm volatile("s_waitcnt vmcnt(0) lgkmcnt(0)" ::: "memory");
    if (kt < 31) __builtin_amdgcn_s_barrier();
    cw = cwn;
    cb = (cb == 2) ? 0 : cb + 1;
  }
  accl += __shfl_xor(accl, 16);
  accl += __shfl_xor(accl, 32);
  bool zrow = (accl == 0.0f);
  float pscale = zrow ? 0.0f : 1.0f / accl;
  float pbias = zrow ? (1.0f / 2048.0f) : 0.0f;

  __syncthreads();   // all waves done reading kls before pass-2 restaging

  // ---------- pass 2: write attn, accumulate PV ----------
  float* attb = attn_out + (size_t)bh * Nn * Nn + (size_t)(q0 + l15) * Nn;
  char* pwave = (char*)pls + w * 2048;
  int pwbase = l15 * 128;
  f32x4 ctx[4];
#pragma unroll
  for (int i = 0; i < 4; ++i) ctx[i] = (f32x4){0.f, 0.f, 0.f, 0.f};

  cw = cp[lane];
  __builtin_amdgcn_sched_barrier(0);
  {
    char* kd = (char*)kls + w * 2048;
    char* vd = (char*)vls + w * 2048;
    stage16(Kg + ksw0, kd);                   // K0,V0 -> buf0
    stage16(Kg + ksw1, kd + 1024);
    stage16(VgR0, vd);
    stage16(VgR1, vd + 1024);
    stage16(Kg + 8192 + ksw0, kd + 8192);     // K1,V1 -> buf1
    stage16(Kg + 8192 + ksw1, kd + 8192 + 1024);
    stage16(VgR0 + 128, vd + 8192);
    stage16(VgR1 + 128, vd + 8192 + 1024);
  }
  asm volatile("s_waitcnt vmcnt(4) lgkmcnt(0)" ::: "memory");  // drain cw,K0,V0
  __builtin_amdgcn_s_barrier();

  cb = 0;
#pragma unroll 1
  for (int kt = 0; kt < 32; ++kt) {
    u32x4 cwn = cw;
    if (kt < 31) cwn = cp[(kt + 1) * 64 + lane];   // code first (oldest)
    __builtin_amdgcn_sched_barrier(0);
    if (kt < 30) {
      int nb = cb ? cb - 1 : 2;                    // (kt+2) % 3
      const char* Kn = Kg + (size_t)(kt + 2) * 8192;
      char* kd = (char*)kls + nb * 8192 + w * 2048;
      char* vd = (char*)vls + nb * 8192 + w * 2048;
      stage16(Kn + ksw0, kd);
      stage16(Kn + ksw1, kd + 1024);
      stage16(VgR0 + (size_t)(kt + 2) * 128, vd);
      stage16(VgR1 + (size_t)(kt + 2) * 128, vd + 1024);
    }
    __builtin_amdgcn_sched_barrier(0);
    const char* kcur = (const char*)kls + cb * 8192;
    const char* vcur = (const char*)vls + cb * 8192;
#pragma unroll
    for (int ks = 0; ks < 4; ++ks) {
      unsigned int cword = cw[ks];
      f32x4 acc;
#pragma unroll
      for (int j = 0; j < 4; ++j)
        acc[j] = __int_as_float(
            __builtin_amdgcn_ds_bpermute((cword >> (8 * j)) & 0xFF, lut_i));
      acc = MFMA16(ld8((const u16*)(kcur + ra + ks * 2048)), bq0, acc);
      acc = MFMA16(ld8((const u16*)(kcur + (ra ^ 64) + ks * 2048)), bq1, acc);
      f32x4 p;
#pragma unroll
      for (int j = 0; j < 4; ++j)
        p[j] = __builtin_amdgcn_exp2f(acc[j]) * pscale + pbias;
      __builtin_nontemporal_store(p, (f32x4*)(attb + kt * 64 + ks * 16 + l4 * 4));
      s16x4 pb;
#pragma unroll
      for (int j = 0; j < 4; ++j)
        pb[j] = (short)__builtin_bit_cast(u16, (__bf16)p[j]);
      *(s16x4*)(pwave + pwbase + ((ks * 32 + l4 * 8) ^ sw)) = pb;
    }
    // PV: read P as A-fragments, staged V as B-fragments
    bf16x8 pa0 = ld8((const u16*)(pwave + pwbase + ((l4 * 16) ^ sw)));
    bf16x8 pa1 = ld8((const u16*)(pwave + pwbase + ((l4 * 16 + 64) ^ sw)));
#pragma unroll
    for (int ds_ = 0; ds_ < 4; ++ds_) {
      bf16x8 v0 = ld8((const u16*)(vcur + ra + ds_ * 2048));
      bf16x8 v1 = ld8((const u16*)(vcur + (ra ^ 64) + ds_ * 2048));
      ctx[ds_] = MFMA16(pa0, v0, ctx[ds_]);
      ctx[ds_] = MFMA16(pa1, v1, ctx[ds_]);
    }
    // drain stage(kt+1)+code(kt+1); leave stage(kt+2) (4) + 4 stores in flight
    if (kt < 30)
      asm volatile("s_waitcnt vmcnt(8) lgkmcnt(0)" ::: "memory");
    else if (kt == 30)
      asm volatile("s_waitcnt vmcnt(4) lgkmcnt(0)" ::: "memory");
    if (kt < 31) __builtin_amdgcn_s_barrier();
    cw = cwn;
    cb = (cb == 2) ? 0 : cb + 1;
  }

#pragma unroll
  for (int ds_ = 0; ds_ < 4; ++ds_) {
    int col = h * 64 + ds_ * 16 + l15;
#pragma unroll
    for (int j = 0; j < 4; ++j) {
      int qrow = q0 + l4 * 4 + j;
      ctx_ws[(size_t)(b * Nn + qrow) * Dd + col] = f2bf(ctx[ds_][j]);
    }
  }
}

// ================= out GEMM + residual + LayerNorm =================
__global__ __launch_bounds__(256) void outln_kernel(const u16* ctxb, const u16* woT,
                                                    const float* bo, const float* xf,
                                                    const float* ln_g, const float* ln_b,
                                                    float* yout) {
  __shared__ float ytile[32][257];
  __shared__ float muS[32], rvS[32];
  int bm0 = blockIdx.x * 32;
  int w = threadIdx.x >> 6, lane = threadIdx.x & 63;
  int l15 = lane & 15, l4 = lane >> 4;
  f32x4 acc[2][4];
#pragma unroll
  for (int q = 0; q < 2; ++q)
#pragma unroll
    for (int i = 0; i < 4; ++i) acc[q][i] = (f32x4){0.f, 0.f, 0.f, 0.f};
#pragma unroll
  for (int kst = 0; kst < 8; ++kst) {
    int k0 = kst * 32 + l4 * 8;
    bf16x8 a0 = ld8(ctxb + (size_t)(bm0 + l15) * 256 + k0);
    bf16x8 a1 = ld8(ctxb + (size_t)(bm0 + 16 + l15) * 256 + k0);
#pragma unroll
    for (int ds_ = 0; ds_ < 4; ++ds_) {
      bf16x8 bw = ld8(woT + (size_t)(w * 64 + ds_ * 16 + l15) * 256 + k0);
      acc[0][ds_] = MFMA16(a0, bw, acc[0][ds_]);
      acc[1][ds_] = MFMA16(a1, bw, acc[1][ds_]);
    }
  }
#pragma unroll
  for (int qs = 0; qs < 2; ++qs)
#pragma unroll
    for (int ds_ = 0; ds_ < 4; ++ds_) {
      int col = w * 64 + ds_ * 16 + l15;
      float bof = bo[col];
#pragma unroll
      for (int j = 0; j < 4; ++j) {
        int row = qs * 16 + l4 * 4 + j;
        ytile[row][col] = acc[qs][ds_][j] + bof + xf[(size_t)(bm0 + row) * 256 + col];
      }
    }
  __syncthreads();
  int row = threadIdx.x >> 3, seg = threadIdx.x & 7;
  float ps = 0.f, pq = 0.f;
#pragma unroll
  for (int c = 0; c < 32; ++c) {
    float v = ytile[row][seg * 32 + c];
    ps += v; pq += v * v;
  }
  ps += __shfl_xor(ps, 1); pq += __shfl_xor(pq, 1);
  ps += __shfl_xor(ps, 2); pq += __shfl_xor(pq, 2);
  ps += __shfl_xor(ps, 4); pq += __shfl_xor(pq, 4);
  if (seg == 0) {
    float mu = ps * (1.0f / 256.0f);
    muS[row] = mu;
    rvS[row] = rsqrtf(pq * (1.0f / 256.0f) - mu * mu + 1e-5f);
  }
  __syncthreads();
  float mu = muS[row], rv = rvS[row];
  float* yr = yout + (size_t)(bm0 + row) * 256;
#pragma unroll
  for (int c0 = 0; c0 < 32; c0 += 4) {
    int c = seg * 32 + c0;
    float4 o;
    o.x = (ytile[row][c + 0] - mu) * rv * ln_g[c + 0] + ln_b[c + 0];
    o.y = (ytile[row][c + 1] - mu) * rv * ln_g[c + 1] + ln_b[c + 1];
    o.z = (ytile[row][c + 2] - mu) * rv * ln_g[c + 2] + ln_b[c + 2];
    o.w = (ytile[row][c + 3] - mu) * rv * ln_g[c + 3] + ln_b[c + 3];
    *(float4*)(yr + c) = o;
  }
}

extern "C" void kernel_launch(void* const* d_in, const int* in_sizes, int n_in,
                              void* d_out, int out_size, void* d_ws, size_t ws_size,
                              hipStream_t stream) {
  const float* nodes = (const float*)d_in[0];
  const int* node_types = (const int*)d_in[1];
  const int* edge_types = (const int*)d_in[2];
  const float* adjacency = (const float*)d_in[3];
  const float* nte = (const float*)d_in[4];
  const float* ee = (const float*)d_in[5];
  const float* Wq = (const float*)d_in[6];
  const float* bq = (const float*)d_in[7];
  const float* Wk = (const float*)d_in[8];
  const float* bk = (const float*)d_in[9];
  const float* Wv = (const float*)d_in[10];
  const float* bv = (const float*)d_in[11];
  const float* Wo = (const float*)d_in[12];
  const float* bo = (const float*)d_in[13];
  const float* ln_g = (const float*)d_in[14];
  const float* ln_b = (const float*)d_in[15];

  float* y = (float*)d_out;
  float* attn = y + (size_t)Bsz * Nn * Dd;

  char* ws = (char*)d_ws;
  float* xf = (float*)(ws + OFF_X);
  u16* xbf = (u16*)(ws + OFF_XBF);
  u16* wqkvT = (u16*)(ws + OFF_WQKVT);
  u16* woT = (u16*)(ws + OFF_WOT);
  float* bqkv = (float*)(ws + OFF_BQKV);
  u16* Qb = (u16*)(ws + OFF_Q);
  u16* Kb = (u16*)(ws + OFF_K);
  u16* Vb = (u16*)(ws + OFF_V);
  u16* Vtb = (u16*)(ws + OFF_VT);
  u16* ctxb = (u16*)(ws + OFF_CTX);
  u8* codes = (u8*)(ws + OFF_CODES);

  pack_kernel<<<1027, 256, 0, stream>>>(Wq, Wk, Wv, Wo, bq, bk, bv, wqkvT, woT, bqkv);
  embed_kernel<<<2048, 256, 0, stream>>>(nodes, node_types, nte, xf, xbf);
  maskpack_kernel<<<4096, 256, 0, stream>>>(node_types, edge_types, adjacency, codes);
  qkv_kernel<<<dim3(12, 128), 256, 0, stream>>>(xbf, wqkvT, bqkv, Qb, Kb, Vb);
  vtrans_kernel<<<dim3(32, 16), 256, 0, stream>>>(Vb, Vtb);
  attn_kernel<<<512, 256, 0, stream>>>(Qb, Kb, Vtb, codes, ee, attn, ctxb);
  outln_kernel<<<256, 256, 0, stream>>>(ctxb, woT, bo, xf, ln_g, ln_b, y);
}